// Round 7
// baseline (751.278 us; speedup 1.0000x reference)
//
#include <hip/hip_runtime.h>
#include <hip/hip_bf16.h>
#include <math.h>

#define IN_DIM 128
#define LAT 32
#define HID 128
#define RSHIFT 8          // nodes per bucket = 256
#define RANGE 256
#define KMAX 1024
#define PART_CH 16384
#define GIN_ROWS 32       // rows per block in gemm_in

typedef unsigned short u16;

__device__ __forceinline__ float bf2f(u16 v) {
    return __uint_as_float(((unsigned int)v) << 16);
}
__device__ __forceinline__ u16 f2bf(float f) {
    unsigned int u = __float_as_uint(f);
    u += 0x7fff + ((u >> 16) & 1);   // round-to-nearest-even
    return (u16)(u >> 16);
}
__device__ __forceinline__ float bflo(unsigned int w) {
    return __uint_as_float(w << 16);
}
__device__ __forceinline__ float bfhi(unsigned int w) {
    return __uint_as_float(w & 0xffff0000u);
}

// ---------------- setup ----------------

__global__ void pmap_kernel(const int* __restrict__ batch, int* __restrict__ pmap, int N) {
    int v = blockIdx.x * blockDim.x + threadIdx.x;
    if (v >= N) return;
    int b = batch[v];
    int prev = (v == 0) ? -1 : batch[v - 1];
    pmap[v] = (b != prev) ? (b + 1) : 0;
}

// ---------------- radix-partition CSR build ----------------

__global__ void bucket_hist_kernel(const int* __restrict__ ei, int* __restrict__ bucketTot,
                                   long long E, int K) {
    __shared__ int hist[KMAX];
    for (int b = threadIdx.x; b < K; b += blockDim.x) hist[b] = 0;
    __syncthreads();
    long long tid = (long long)blockIdx.x * blockDim.x + threadIdx.x;
    long long stride = (long long)gridDim.x * blockDim.x;
    for (long long e = tid; e < E; e += stride) {
        int d = ei[E + e];
        atomicAdd(&hist[d >> RSHIFT], 1);
    }
    __syncthreads();
    for (int b = threadIdx.x; b < K; b += blockDim.x) {
        int h = hist[b];
        if (h) atomicAdd(&bucketTot[b], h);
    }
}

__global__ void bucket_scan_kernel(const int* __restrict__ bucketTot, int* __restrict__ bucketStart,
                                   int* __restrict__ bucketCursor, int K, int Etot,
                                   int* __restrict__ rowptr, int N) {
    __shared__ int s[KMAX];
    int t = threadIdx.x;
    int v = (t < K) ? bucketTot[t] : 0;
    s[t] = v;
    __syncthreads();
    for (int off = 1; off < KMAX; off <<= 1) {
        int tmp = (t >= off) ? s[t - off] : 0;
        __syncthreads();
        s[t] += tmp;
        __syncthreads();
    }
    if (t < K) {
        int excl = s[t] - v;
        bucketStart[t] = excl;
        bucketCursor[t] = excl;
    }
    if (t == 0) {
        bucketStart[K] = Etot;
        rowptr[N] = Etot;
    }
}

__global__ void partition_kernel(const int* __restrict__ ei, int* __restrict__ bucketCursor,
                                 unsigned int* __restrict__ pairs, long long E, int K) {
    __shared__ int hist[KMAX];
    __shared__ int off[KMAX];
    __shared__ int cur[KMAX];
    int t = threadIdx.x;
    for (int b = t; b < K; b += blockDim.x) { hist[b] = 0; cur[b] = 0; }
    __syncthreads();
    long long e0 = (long long)blockIdx.x * PART_CH;
    int cnt = (int)min((long long)PART_CH, E - e0);
    for (int i = t; i < cnt; i += blockDim.x) {
        int d = ei[E + e0 + i];
        atomicAdd(&hist[d >> RSHIFT], 1);
    }
    __syncthreads();
    for (int b = t; b < K; b += blockDim.x) {
        int h = hist[b];
        off[b] = h ? atomicAdd(&bucketCursor[b], h) : 0;
    }
    __syncthreads();
    for (int i = t; i < cnt; i += blockDim.x) {
        long long e = e0 + i;
        unsigned int s = (unsigned int)ei[e];
        int d = ei[E + e];
        int b = d >> RSHIFT;
        int p = off[b] + atomicAdd(&cur[b], 1);
        pairs[p] = (s << RSHIFT) | (unsigned int)(d & (RANGE - 1));
    }
}

__global__ void build_csr_kernel(const unsigned int* __restrict__ pairs,
                                 const int* __restrict__ bucketStart,
                                 int* __restrict__ rowptr, float* __restrict__ dinv,
                                 int* __restrict__ csr_src, int N) {
    __shared__ int hist[RANGE];
    __shared__ int scanb[RANGE];
    __shared__ int cursor[RANGE];
    int b = blockIdx.x;
    int t = threadIdx.x;
    int base = b << RSHIFT;
    int s0 = bucketStart[b];
    int s1 = bucketStart[b + 1];
    int cnt = s1 - s0;
    hist[t] = 0;
    __syncthreads();
    for (int i = t; i < cnt; i += RANGE) {
        unsigned int p = pairs[s0 + i];
        atomicAdd(&hist[p & (RANGE - 1)], 1);
    }
    __syncthreads();
    int deg = hist[t];
    scanb[t] = deg;
    __syncthreads();
    for (int off = 1; off < RANGE; off <<= 1) {
        int tmp = (t >= off) ? scanb[t - off] : 0;
        __syncthreads();
        scanb[t] += tmp;
        __syncthreads();
    }
    int excl = scanb[t] - deg;
    int node = base + t;
    if (node < N) {
        rowptr[node] = s0 + excl;
        dinv[node] = rsqrtf((float)(deg + 1));   // +1 self-loop
    }
    cursor[t] = s0 + excl;
    __syncthreads();
    for (int i = t; i < cnt; i += RANGE) {
        unsigned int p = pairs[s0 + i];
        int slot = atomicAdd(&cursor[p & (RANGE - 1)], 1);
        csr_src[slot] = (int)(p >> RSHIFT);
    }
}

// ---------------- input transform: tp1 = (x@W1)*dinv, bf16 ----------------

__global__ void gemm_in_kernel(const float* __restrict__ x, const float* __restrict__ W,
                               const float* __restrict__ dinv, u16* __restrict__ tp, int N) {
    __shared__ float Wl[IN_DIM * LAT];         // 16 KB
    __shared__ float Xl[GIN_ROWS * IN_DIM];    // 16 KB
    int t = threadIdx.x;
    for (int i = t; i < IN_DIM * LAT; i += 256) Wl[i] = W[i];
    long long rowBase = (long long)blockIdx.x * GIN_ROWS;
    int nrow = min(GIN_ROWS, (int)(N - rowBase));
    {
        const float4* x4 = reinterpret_cast<const float4*>(x + rowBase * IN_DIM);
        float4* X4 = reinterpret_cast<float4*>(Xl);
        int nf4 = nrow * (IN_DIM / 4);
        for (int i = t; i < nf4; i += 256) X4[i] = x4[i];   // coalesced
    }
    __syncthreads();
    int g = t >> 5;            // col-group 0..7
    int c = t & 31;
    int r0 = g * 4;            // 4 local rows per group
    float acc0 = 0.f, acc1 = 0.f, acc2 = 0.f, acc3 = 0.f;
#pragma unroll 4
    for (int k = 0; k < IN_DIM; k += 4) {
        float w0 = Wl[(k + 0) * LAT + c];
        float w1 = Wl[(k + 1) * LAT + c];
        float w2 = Wl[(k + 2) * LAT + c];
        float w3 = Wl[(k + 3) * LAT + c];
        float4 xa = *reinterpret_cast<const float4*>(&Xl[(r0 + 0) * IN_DIM + k]);
        float4 xb = *reinterpret_cast<const float4*>(&Xl[(r0 + 1) * IN_DIM + k]);
        float4 xc = *reinterpret_cast<const float4*>(&Xl[(r0 + 2) * IN_DIM + k]);
        float4 xd = *reinterpret_cast<const float4*>(&Xl[(r0 + 3) * IN_DIM + k]);
        acc0 += xa.x * w0 + xa.y * w1 + xa.z * w2 + xa.w * w3;
        acc1 += xb.x * w0 + xb.y * w1 + xb.z * w2 + xb.w * w3;
        acc2 += xc.x * w0 + xc.y * w1 + xc.z * w2 + xc.w * w3;
        acc3 += xd.x * w0 + xd.y * w1 + xd.z * w2 + xd.w * w3;
    }
    long long rr = rowBase + r0;
    if (r0 + 0 < nrow) tp[(rr + 0) * LAT + c] = f2bf(acc0 * dinv[rr + 0]);
    if (r0 + 1 < nrow) tp[(rr + 1) * LAT + c] = f2bf(acc1 * dinv[rr + 1]);
    if (r0 + 2 < nrow) tp[(rr + 2) * LAT + c] = f2bf(acc2 * dinv[rr + 2]);
    if (r0 + 3 < nrow) tp[(rr + 3) * LAT + c] = f2bf(acc3 * dinv[rr + 3]);
}

// ---------------- fused gather + tanh + next-layer GEMM ----------------
// One wave per node. Lane = (edge-slot t = lane>>2, feat-block a = lane&3).
// Each VMEM instr: 64 lanes x 16B = 16 edges' full rows (vs 2 in round 6).

__global__ void gather_fused_kernel(const int* __restrict__ rowptr, const int* __restrict__ csr_src,
                                    const u16* __restrict__ tp, const float* __restrict__ dinv,
                                    const float* __restrict__ bcur, const int* __restrict__ pmap,
                                    float* __restrict__ pooled, int colOff,
                                    const float* __restrict__ Wnext, u16* __restrict__ tpNext,
                                    int N, int Ei) {
    __shared__ float Wl[LAT * LAT];
    if (Wnext) {   // grid-uniform branch
        for (int i = threadIdx.x; i < LAT * LAT; i += blockDim.x) Wl[i] = Wnext[i];
        __syncthreads();
    }
    int wv = threadIdx.x >> 6;
    int lane = threadIdx.x & 63;
    int v = blockIdx.x * 4 + wv;
    if (v >= N) return;
    int a = lane & 3;          // feat block: elems 8a..8a+7
    int t = lane >> 2;         // edge slot 0..15
    int start = rowptr[v], end = rowptr[v + 1];   // wave-uniform

    float c0 = 0.f, c1 = 0.f, c2 = 0.f, c3 = 0.f,
          c4 = 0.f, c5 = 0.f, c6 = 0.f, c7 = 0.f;

    for (int sb = start; sb < end; sb += 64) {
        int li = sb + lane;
        if (li > Ei - 1) li = Ei - 1;
        int s_all = csr_src[li];                  // 64 indices, coalesced
#pragma unroll
        for (int it = 0; it < 4; it++) {
            int eb = sb + it * 16;
            if (eb >= end) break;                 // wave-uniform break
            int e = eb + t;
            int sj = __shfl(s_all, it * 16 + t, 64);   // ds_bpermute, per-lane idx
            float m = 1.f;
            if (e >= end) { m = 0.f; sj = 0; }
            const uint4 w = *reinterpret_cast<const uint4*>(
                tp + (((size_t)sj) << 5) + (a << 3));  // 16B = 8 feats
            c0 += m * bflo(w.x);  c1 += m * bfhi(w.x);
            c2 += m * bflo(w.y);  c3 += m * bfhi(w.y);
            c4 += m * bflo(w.z);  c5 += m * bfhi(w.z);
            c6 += m * bflo(w.w);  c7 += m * bfhi(w.w);
        }
    }
    // butterfly reduce over edge-slots (lane bits 2..5)
#pragma unroll
    for (int d = 4; d <= 32; d <<= 1) {
        c0 += __shfl_xor(c0, d, 64);
        c1 += __shfl_xor(c1, d, 64);
        c2 += __shfl_xor(c2, d, 64);
        c3 += __shfl_xor(c3, d, 64);
        c4 += __shfl_xor(c4, d, 64);
        c5 += __shfl_xor(c5, d, 64);
        c6 += __shfl_xor(c6, d, 64);
        c7 += __shfl_xor(c7, d, 64);
    }
    // remap: lane f takes feat f = 8*(f>>3) + (f&7) from lane (f>>3)
    int f = lane & 31;
    int srcl = f >> 3;
    float r0 = __shfl(c0, srcl, 64), r1 = __shfl(c1, srcl, 64);
    float r2 = __shfl(c2, srcl, 64), r3 = __shfl(c3, srcl, 64);
    float r4 = __shfl(c4, srcl, 64), r5 = __shfl(c5, srcl, 64);
    float r6 = __shfl(c6, srcl, 64), r7 = __shfl(c7, srcl, 64);
    int b = f & 7;
    float sv = (b == 0) ? r0 : (b == 1) ? r1 : (b == 2) ? r2 : (b == 3) ? r3
             : (b == 4) ? r4 : (b == 5) ? r5 : (b == 6) ? r6 : r7;

    float dv = dinv[v];
    float self = bf2f(tp[((size_t)v << 5) + f]);
    float hv = tanhf(dv * (sv + self) + bcur[f]);
    int pg = pmap[v];
    if (pg && lane < 32) pooled[(size_t)(pg - 1) * (3 * LAT) + colOff + f] = hv;
    if (Wnext) {
        float acc2 = 0.f;
#pragma unroll
        for (int k = 0; k < LAT; k++) acc2 += __shfl(hv, k, 32) * Wl[k * LAT + f];
        if (lane < 32) tpNext[((size_t)v << 5) + f] = f2bf(acc2 * dv);
    }
}

// ---------------- MLP head ----------------

__global__ void mlp_head_kernel(const float* __restrict__ pooled,
                                const float* __restrict__ Wl1, const float* __restrict__ bl1,
                                const float* __restrict__ Wl2, const float* __restrict__ bl2,
                                float* __restrict__ out, int G) {
    __shared__ float prow[3 * LAT];
    __shared__ float red0[HID];
    __shared__ float red1[HID];
    int g = blockIdx.x;
    int j = threadIdx.x;
    if (j < 3 * LAT) prow[j] = pooled[(long long)g * (3 * LAT) + j];
    __syncthreads();
    float acc = bl1[j];
#pragma unroll 8
    for (int k = 0; k < 3 * LAT; k++) acc += prow[k] * Wl1[k * HID + j];
    float hj = fmaxf(acc, 0.f);
    red0[j] = hj * Wl2[j * 2 + 0];
    red1[j] = hj * Wl2[j * 2 + 1];
    __syncthreads();
    for (int s = HID / 2; s > 0; s >>= 1) {
        if (j < s) { red0[j] += red0[j + s]; red1[j] += red1[j + s]; }
        __syncthreads();
    }
    if (j == 0) {
        float l0 = red0[0] + bl2[0];
        float l1 = red1[0] + bl2[1];
        float m = fmaxf(l0, l1);
        float lse = m + logf(expf(l0 - m) + expf(l1 - m));
        out[(long long)g * 2 + 0] = l0 - lse;
        out[(long long)g * 2 + 1] = l1 - lse;
    }
}

// ---------------- launch ----------------

extern "C" void kernel_launch(void* const* d_in, const int* in_sizes, int n_in,
                              void* d_out, int out_size, void* d_ws, size_t ws_size,
                              hipStream_t stream) {
    const float* x    = (const float*)d_in[0];
    const int*   ei   = (const int*)d_in[1];
    const int*   batch= (const int*)d_in[2];
    const float* W1   = (const float*)d_in[3];
    const float* b1   = (const float*)d_in[4];
    const float* W2   = (const float*)d_in[5];
    const float* b2   = (const float*)d_in[6];
    const float* W3   = (const float*)d_in[7];
    const float* b3   = (const float*)d_in[8];
    const float* Wl1  = (const float*)d_in[9];
    const float* bl1  = (const float*)d_in[10];
    const float* Wl2  = (const float*)d_in[11];
    const float* bl2  = (const float*)d_in[12];
    float* out = (float*)d_out;

    const int N = in_sizes[2];
    const long long E = (long long)in_sizes[1] / 2;
    const int G = out_size / 2;
    const int K = (N + RANGE - 1) >> RSHIFT;

    // workspace layout
    char* ws = (char*)d_ws;
    size_t off = 0;
    char*  bufA    = ws + off;           off += (size_t)E * 4;            // pairs (u32 E), later tpA (bf16 N*32)
    char*  bufB    = ws + off;           off += (size_t)N * LAT * 2;      // tpB (bf16)
    int*   csr_src = (int*)  (ws + off); off += (size_t)E * 4;
    float* dinv    = (float*)(ws + off); off += (size_t)N * 4;
    int*   rowptr  = (int*)  (ws + off); off += (size_t)(N + 1) * 4;
    int*   pmap    = (int*)  (ws + off); off += (size_t)N * 4;
    float* pooled  = (float*)(ws + off); off += (size_t)G * (3 * LAT) * 4;
    int*   bucketTot    = (int*)(ws + off); off += (KMAX + 1) * 4;
    int*   bucketStart  = (int*)(ws + off); off += (KMAX + 1) * 4;
    int*   bucketCursor = (int*)(ws + off); off += KMAX * 4;

    unsigned int* pairs = (unsigned int*)bufA;   // dead before gemm_in writes tpA
    u16* tpA = (u16*)bufA;
    u16* tpB = (u16*)bufB;

    const int BS = 256;
    const int gatherBlocks = (N + 3) / 4;        // 1 wave per node, 4 waves/block
    const int ginBlocks = (N + GIN_ROWS - 1) / GIN_ROWS;
    const int partBlocks = (int)((E + PART_CH - 1) / PART_CH);

    // ---- CSR build via radix partition ----
    hipMemsetAsync(bucketTot, 0, (size_t)(KMAX + 1) * 4, stream);
    pmap_kernel<<<(N + BS - 1) / BS, BS, 0, stream>>>(batch, pmap, N);
    bucket_hist_kernel<<<256, BS, 0, stream>>>(ei, bucketTot, E, K);
    bucket_scan_kernel<<<1, KMAX, 0, stream>>>(bucketTot, bucketStart, bucketCursor, K, (int)E, rowptr, N);
    partition_kernel<<<partBlocks, BS, 0, stream>>>(ei, bucketCursor, pairs, E, K);
    build_csr_kernel<<<K, RANGE, 0, stream>>>(pairs, bucketStart, rowptr, dinv, csr_src, N);

    // ---- layer 1 transform ----
    gemm_in_kernel<<<ginBlocks, BS, 0, stream>>>(x, W1, dinv, tpA, N);

    // ---- fused layers ----
    gather_fused_kernel<<<gatherBlocks, BS, 0, stream>>>(rowptr, csr_src, tpA, dinv, b1, pmap,
                                                         pooled, 0, W2, tpB, N, (int)E);
    gather_fused_kernel<<<gatherBlocks, BS, 0, stream>>>(rowptr, csr_src, tpB, dinv, b2, pmap,
                                                         pooled, LAT, W3, tpA, N, (int)E);
    gather_fused_kernel<<<gatherBlocks, BS, 0, stream>>>(rowptr, csr_src, tpA, dinv, b3, pmap,
                                                         pooled, 2 * LAT, (const float*)nullptr,
                                                         (u16*)nullptr, N, (int)E);

    // ---- MLP head ----
    mlp_head_kernel<<<G, HID, 0, stream>>>(pooled, Wl1, bl1, Wl2, bl2, out, G);
}